// Round 15
// baseline (505.357 us; speedup 1.0000x reference)
//
#include <hip/hip_runtime.h>
#include <math.h>

#define SQ 2048      // seq len
#define DE 512       // d_embedding
#define DH 64        // d_head
#define CW 128       // half-window
#define W2 256       // window width
#define NH 8         // heads
#define NQ 2         // queries per block (NQ=2: same per-thread load as R10, 2x blocks)
#define UW (W2 + NQ - 1)  // union window width = 257
#define NT 256       // threads per block -> 4 waves -> 4 barrier domains/CU
#define NW 4         // waves per block

// prep: packed-float4 weight layouts, coalesced READS.
// Pass A (e-fastest index): WT4[h][e/4][c][e%4] <- Wq/Wk/Wvd[(h*DH+c)*DE+e]
// Pass B (c-fastest index): VT4[h][c/4][e][c%4] <- Wvu[(h*DE+e)*DH+c]
__global__ __launch_bounds__(256) void prep_kernel(
    const float* __restrict__ Wq, const float* __restrict__ Wk,
    const float* __restrict__ Wvd, const float* __restrict__ Wvu,
    float* __restrict__ WT4q, float* __restrict__ WT4k, float* __restrict__ WT4v,
    float* __restrict__ VT4) {
  int i = blockIdx.x * 256 + threadIdx.x;
  if (i < NH * DE * DH) {
    int e = i & 511;
    int c = (i >> 9) & 63;
    int h = i >> 15;
    int w4i = ((h * 128 + (e >> 2)) * 64 + c) * 4 + (e & 3);
    WT4q[w4i] = Wq[i];
    WT4k[w4i] = Wk[i];
    WT4v[w4i] = Wvd[i];
    int c2 = i & 63;
    int e2 = (i >> 6) & 511;
    int h2 = i >> 15;
    int v4i = ((h2 * 16 + (c2 >> 2)) * 512 + e2) * 4 + (c2 & 3);
    VT4[v4i] = Wvu[i];
  }
}

// qkv0: x -> cur copy + q/kT/v for head 0
__global__ __launch_bounds__(NT) void qkv0_kernel(
    const float* __restrict__ x,
    const float4* __restrict__ Wq4, const float4* __restrict__ Wk4,
    const float4* __restrict__ Wv4, float* __restrict__ cur,
    float* __restrict__ q, float* __restrict__ kT, float* __restrict__ v) {
  __shared__ float xL[NQ][DE];             // 4 KB
  __shared__ float qP[NW][3][NQ][DH];      // 6 KB
  int tid = threadIdx.x, lane = tid & 63, wv = tid >> 6;
  int j0 = blockIdx.x * NQ;

  float4 xv = ((const float4*)(x + (size_t)j0 * DE))[tid];
  ((float4*)xL)[tid] = xv;
  ((float4*)(cur + (size_t)j0 * DE))[tid] = xv;
  __syncthreads();

  float aq[NQ] = {0, 0}, ak[NQ] = {0, 0}, av[NQ] = {0, 0};
  int e0 = wv * 128;
#pragma unroll
  for (int i4 = 0; i4 < 32; i4++) {
    int widx = (wv * 32 + i4) * 64 + lane;
    float4 wq4 = Wq4[widx];
    float4 wk4 = Wk4[widx];
    float4 wv4 = Wv4[widx];
#pragma unroll
    for (int r = 0; r < NQ; r++) {
      float4 xr = ((const float4*)&xL[r][e0])[i4];
      aq[r] += xr.x * wq4.x + xr.y * wq4.y + xr.z * wq4.z + xr.w * wq4.w;
      ak[r] += xr.x * wk4.x + xr.y * wk4.y + xr.z * wk4.z + xr.w * wk4.w;
      av[r] += xr.x * wv4.x + xr.y * wv4.y + xr.z * wv4.z + xr.w * wv4.w;
    }
  }
#pragma unroll
  for (int r = 0; r < NQ; r++) {
    qP[wv][0][r][lane] = aq[r];
    qP[wv][1][r][lane] = ak[r];
    qP[wv][2][r][lane] = av[r];
  }
  __syncthreads();
  for (int i = tid; i < 3 * NQ * DH; i += NT) {
    int o = i >> 7;              // NQ*DH = 128
    int rem = i & 127;
    int r = rem >> 6, c = rem & 63;
    float s = 0;
#pragma unroll
    for (int w = 0; w < NW; w++) s += qP[w][o][r][c];
    if (o == 0) q[(size_t)(j0 + r) * DH + c] = s;
    else if (o == 1) kT[(size_t)c * SQ + (j0 + r)] = s;
    else v[(size_t)(j0 + r) * DH + c] = s;
  }
}

// fused: attn(head h) [+ qkv(head h+1)]
// flags bit0: last head -> out = cur/8 ; bit1: compute next-head qkv
__global__ __launch_bounds__(NT) void fused_kernel(
    float* __restrict__ cur,
    const float* __restrict__ q, const float* __restrict__ kT,
    const float* __restrict__ v, const float4* __restrict__ VT4h,
    const float4* __restrict__ Wq4n, const float4* __restrict__ Wk4n,
    const float4* __restrict__ Wv4n,
    float* __restrict__ qn, float* __restrict__ kTn, float* __restrict__ vn,
    float* __restrict__ out, int flags) {
  __shared__ float qL[NQ][DH];             // 0.5 KB
  __shared__ float sL[NQ][W2];             // 2 KB
  __shared__ float pL[NW][NQ][DH];         // 2 KB
  __shared__ float dL[NQ][DH];             // 0.5 KB
  __shared__ float yL[NQ][DE];             // 4 KB
  __shared__ float qP[NW][3][NQ][DH];      // 6 KB  -> ~15 KB total

  int tid = threadIdx.x, lane = tid & 63, wv = tid >> 6;
  int j0 = blockIdx.x * NQ;

  // P0: stage q rows (NQ*DH = 128)
  if (tid < NQ * DH) ((float*)qL)[tid] = q[(size_t)j0 * DH + tid];
  __syncthreads();

  // P1: scores; thread covers goff = tid (+256 for tid 0)
  for (int goff = tid; goff < UW; goff += NT) {
    int g = j0 - CW + goff;
    bool valid = (g >= 0 && g < SQ);
    int gc = valid ? g : 0;
    float acc[NQ] = {0, 0};
#pragma unroll
    for (int d8 = 0; d8 < 8; d8++) {
      float kc[8];
#pragma unroll
      for (int u = 0; u < 8; u++) kc[u] = kT[(size_t)(d8 * 8 + u) * SQ + gc];
#pragma unroll
      for (int r = 0; r < NQ; r++) {
        float4 q0 = ((const float4*)qL[r])[2 * d8];
        float4 q1 = ((const float4*)qL[r])[2 * d8 + 1];
        acc[r] += q0.x * kc[0] + q0.y * kc[1] + q0.z * kc[2] + q0.w * kc[3] +
                  q1.x * kc[4] + q1.y * kc[5] + q1.z * kc[6] + q1.w * kc[7];
      }
    }
#pragma unroll
    for (int r = 0; r < NQ; r++) {
      int p = goff - r;
      if (p >= 0 && p < W2) sL[r][p] = valid ? acc[r] * 0.125f : -INFINITY;
    }
  }
  __syncthreads();

  // P2: softmax; waves 0-1 own rows 0-1
  if (wv < NQ) {
    int r = wv;
    float m = -INFINITY;
#pragma unroll
    for (int t = 0; t < 4; t++) m = fmaxf(m, sL[r][lane + 64 * t]);
#pragma unroll
    for (int off = 32; off; off >>= 1) m = fmaxf(m, __shfl_xor(m, off));
    float ex[4], ss = 0;
#pragma unroll
    for (int t = 0; t < 4; t++) {
      ex[t] = __expf(sL[r][lane + 64 * t] - m);
      ss += ex[t];
    }
#pragma unroll
    for (int off = 32; off; off >>= 1) ss += __shfl_xor(ss, off);
    float inv = 1.0f / ss;
#pragma unroll
    for (int t = 0; t < 4; t++) sL[r][lane + 64 * t] = ex[t] * inv;
  }
  __syncthreads();

  // P3: PV; 4 waves x 65 offsets, 5 chunks of 13
  {
    float dacc[NQ] = {0, 0};
    int gbeg = 65 * wv;
#pragma unroll
    for (int ch = 0; ch < 5; ch++) {
      float vc[13];
#pragma unroll
      for (int i = 0; i < 13; i++) {
        int goff = gbeg + ch * 13 + i;
        int g = j0 - CW + goff;
        int gc = g < 0 ? 0 : (g >= SQ ? SQ - 1 : g);
        vc[i] = v[(size_t)gc * DH + lane];
      }
#pragma unroll
      for (int i = 0; i < 13; i++) {
        int goff = gbeg + ch * 13 + i;
        bool act = goff < UW;
#pragma unroll
        for (int r = 0; r < NQ; r++) {
          int p = goff - r;
          float w = (act && p >= 0 && p < W2) ? sL[r][p & 255] : 0.0f;
          dacc[r] += w * vc[i];
        }
      }
    }
#pragma unroll
    for (int r = 0; r < NQ; r++) pL[wv][r][lane] = dacc[r];
  }
  __syncthreads();
  if (tid < NQ * DH) {
    int r = tid >> 6, c = tid & 63;
    float s = 0;
#pragma unroll
    for (int w = 0; w < NW; w++) s += pL[w][r][c];
    dL[r][c] = s;
  }
  __syncthreads();

  // P5: upproj; thread owns e = tid, tid+256
  float c8[8];  // cur row wv (waves 0-1) for renorm, prefetched
  {
    if (wv < NQ) {
      size_t jrow = (size_t)(j0 + wv) * DE;
#pragma unroll
      for (int t = 0; t < 8; t++) c8[t] = cur[jrow + lane + 64 * t];
    }
#pragma unroll
    for (int half = 0; half < 2; half++) {
      int e = tid + 256 * half;
      float cr[NQ];
#pragma unroll
      for (int r = 0; r < NQ; r++) cr[r] = cur[(size_t)(j0 + r) * DE + e];
      float acc[NQ] = {0, 0};
#pragma unroll
      for (int c4 = 0; c4 < 16; c4++) {
        float4 wc4 = VT4h[c4 * 512 + e];
#pragma unroll
        for (int r = 0; r < NQ; r++) {
          float4 df = ((const float4*)dL[r])[c4];
          acc[r] += df.x * wc4.x + df.y * wc4.y + df.z * wc4.z + df.w * wc4.w;
        }
      }
#pragma unroll
      for (int r = 0; r < NQ; r++) yL[r][e] = cr[r] + acc[r];
    }
  }
  __syncthreads();

  // P6: renorm + residual; waves 0-1 own rows 0-1
  if (wv < NQ) {
    int r = wv;
    size_t jrow = (size_t)(j0 + r) * DE;
    float s = 0;
#pragma unroll
    for (int t = 0; t < 8; t++) s += yL[r][lane + 64 * t];
#pragma unroll
    for (int off = 32; off; off >>= 1) s += __shfl_xor(s, off);
    float inv_m1 = 512.0f / s;
    float y2[8], s2 = 0, s2q = 0;
#pragma unroll
    for (int t = 0; t < 8; t++) {
      y2[t] = yL[r][lane + 64 * t] * inv_m1;
      s2 += y2[t];
      s2q += y2[t] * y2[t];
    }
#pragma unroll
    for (int off = 32; off; off >>= 1) {
      s2 += __shfl_xor(s2, off);
      s2q += __shfl_xor(s2q, off);
    }
    float m2 = s2 * (1.0f / 512.0f);
    float var = (s2q - 512.0f * m2 * m2) * (1.0f / 511.0f);
    float isd = 1.0f / sqrtf(var);
#pragma unroll
    for (int t = 0; t < 8; t++) {
      int e = lane + 64 * t;
      float o = (y2[t] - m2) * isd + m2;
      float nc = c8[t] + o;
      cur[jrow + e] = nc;
      yL[r][e] = nc;
      if (flags & 1) out[jrow + e] = nc * (1.0f / NH);
    }
  }
  __syncthreads();

  // P7: next-head qkv; wave e-slice of 128, float4 weight loads
  if (flags & 2) {
    float aq[NQ] = {0, 0}, ak[NQ] = {0, 0}, av[NQ] = {0, 0};
    int e0 = wv * 128;
#pragma unroll
    for (int i4 = 0; i4 < 32; i4++) {
      int widx = (wv * 32 + i4) * 64 + lane;
      float4 wq4 = Wq4n[widx];
      float4 wk4 = Wk4n[widx];
      float4 wv4 = Wv4n[widx];
#pragma unroll
      for (int r = 0; r < NQ; r++) {
        float4 xr = ((const float4*)&yL[r][e0])[i4];
        aq[r] += xr.x * wq4.x + xr.y * wq4.y + xr.z * wq4.z + xr.w * wq4.w;
        ak[r] += xr.x * wk4.x + xr.y * wk4.y + xr.z * wk4.z + xr.w * wk4.w;
        av[r] += xr.x * wv4.x + xr.y * wv4.y + xr.z * wv4.z + xr.w * wv4.w;
      }
    }
#pragma unroll
    for (int r = 0; r < NQ; r++) {
      qP[wv][0][r][lane] = aq[r];
      qP[wv][1][r][lane] = ak[r];
      qP[wv][2][r][lane] = av[r];
    }
    __syncthreads();
    for (int i = tid; i < 3 * NQ * DH; i += NT) {
      int o = i >> 7;
      int rem = i & 127;
      int r = rem >> 6, c = rem & 63;
      float s = 0;
#pragma unroll
      for (int w = 0; w < NW; w++) s += qP[w][o][r][c];
      if (o == 0) qn[(size_t)(j0 + r) * DH + c] = s;
      else if (o == 1) kTn[(size_t)c * SQ + (j0 + r)] = s;
      else vn[(size_t)(j0 + r) * DH + c] = s;
    }
  }
}

extern "C" void kernel_launch(void* const* d_in, const int* in_sizes, int n_in,
                              void* d_out, int out_size, void* d_ws, size_t ws_size,
                              hipStream_t stream) {
  const float* x   = (const float*)d_in[0];
  const float* Wq  = (const float*)d_in[1];
  const float* Wk  = (const float*)d_in[2];
  const float* Wvd = (const float*)d_in[3];
  const float* Wvu = (const float*)d_in[4];
  float* out = (float*)d_out;

  float* ws  = (float*)d_ws;
  float* cur = ws;                    // SQ*DE
  float* qA  = cur + SQ * DE;         // SQ*DH each; k in kT layout [DH][SQ]
  float* kA  = qA + SQ * DH;
  float* vA  = kA + SQ * DH;
  float* qB  = vA + SQ * DH;
  float* kB  = qB + SQ * DH;
  float* vB  = kB + SQ * DH;
  float* WTq = vB + SQ * DH;          // NH*DE*DH each (packed float4 layout)
  float* WTk = WTq + NH * DE * DH;
  float* WTv = WTk + NH * DE * DH;
  float* VT  = WTv + NH * DE * DH;    // NH*DH*DE (packed float4 layout)

  prep_kernel<<<NH * DE * DH / 256, 256, 0, stream>>>(Wq, Wk, Wvd, Wvu,
                                                      WTq, WTk, WTv, VT);
  qkv0_kernel<<<SQ / NQ, NT, 0, stream>>>(
      x, (const float4*)WTq, (const float4*)WTk, (const float4*)WTv,
      cur, qA, kA, vA);

  for (int h = 0; h < NH; h++) {
    const float* qi = (h & 1) ? qB : qA;
    const float* ki = (h & 1) ? kB : kA;
    const float* vi = (h & 1) ? vB : vA;
    float* qo = (h & 1) ? qA : qB;
    float* ko = (h & 1) ? kA : kB;
    float* vo = (h & 1) ? vA : vB;
    const size_t won = (size_t)(h + 1 < NH ? h + 1 : 0) * DE * DH / 4;
    int flags = (h == NH - 1 ? 1 : 0) | (h < NH - 1 ? 2 : 0);
    fused_kernel<<<SQ / NQ, NT, 0, stream>>>(
        cur, qi, ki, vi, (const float4*)VT + (size_t)h * DH * DE / 4,
        (const float4*)WTq + won, (const float4*)WTk + won,
        (const float4*)WTv + won, qo, ko, vo, out, flags);
  }
}